// Round 1
// baseline (1064.699 us; speedup 1.0000x reference)
//
#include <hip/hip_runtime.h>

// cWCT: out = Ls·inv(Lc)·(xc − c_mean) + s_mean  =  T·xc + bias
// B=8, N=256, L=16384. fp32 in/out; bf16 MFMA for the two big GEMMs.

#define BATCH 8
#define NF    256
#define LSP   16384
#define EPS_J 2e-5f

typedef float f32x4  __attribute__((ext_vector_type(4)));
typedef short bf16x8 __attribute__((ext_vector_type(8)));
typedef short short4v __attribute__((ext_vector_type(4)));

__device__ __forceinline__ short f2bf(float f) {
    unsigned u = __float_as_uint(f);
    u = (u + 0x7FFFu + ((u >> 16) & 1u)) >> 16;   // RNE truncate to bf16
    return (short)u;
}

// ---------------------------------------------------------------------------
// K1: batched syrk  gram[m] += A·Aᵀ (bf16 MFMA, split-K) + fp32 row sums.
// grid (splitk=16, m=16), 1024 threads (16 waves, each a 64x64 tile of 256x256)
// ---------------------------------------------------------------------------
__global__ __launch_bounds__(1024) void k_cov(const float* __restrict__ cont,
                                              const float* __restrict__ styl,
                                              float* __restrict__ gram,
                                              float* __restrict__ rowsum) {
    const int kc = blockIdx.x;
    const int m  = blockIdx.y;
    const float* __restrict__ src = (m < BATCH)
        ? cont + (size_t)m * NF * LSP
        : styl + (size_t)(m - BATCH) * NF * LSP;

    __shared__ short lds[256][72];   // 256 rows x 64 k (bf16), pad to 72

    const int t    = threadIdx.x;
    const int lane = t & 63;
    const int w    = t >> 6;
    const int wi   = (w & 3) * 64;
    const int wj   = (w >> 2) * 64;
    const int fr   = t >> 4;          // staging row base
    const int fc   = (t & 15) * 4;    // staging col

    f32x4 acc[4][4];
    #pragma unroll
    for (int i = 0; i < 4; ++i)
        #pragma unroll
        for (int j = 0; j < 4; ++j) { f32x4 z = {0.f, 0.f, 0.f, 0.f}; acc[i][j] = z; }

    float rs[4] = {0.f, 0.f, 0.f, 0.f};

    const size_t kbase = (size_t)kc * 1024;
    float4 pre[4];
    #pragma unroll
    for (int j = 0; j < 4; ++j)
        pre[j] = *(const float4*)(src + (size_t)(fr + j * 64) * LSP + kbase + fc);

    for (int step = 0; step < 16; ++step) {
        __syncthreads();
        #pragma unroll
        for (int j = 0; j < 4; ++j) {
            float4 v = pre[j];
            rs[j] += v.x + v.y + v.z + v.w;
            short4v b4 = { f2bf(v.x), f2bf(v.y), f2bf(v.z), f2bf(v.w) };
            *(short4v*)&lds[fr + j * 64][fc] = b4;
        }
        __syncthreads();
        if (step < 15) {
            const size_t k0n = kbase + (size_t)(step + 1) * 64;
            #pragma unroll
            for (int j = 0; j < 4; ++j)
                pre[j] = *(const float4*)(src + (size_t)(fr + j * 64) * LSP + k0n + fc);
        }
        #pragma unroll
        for (int ks = 0; ks < 2; ++ks) {
            const int kk   = ks * 32 + (lane >> 4) * 8;
            const int rsel = lane & 15;
            bf16x8 af[4], bfv[4];
            #pragma unroll
            for (int mi = 0; mi < 4; ++mi)
                af[mi] = *(const bf16x8*)&lds[wi + mi * 16 + rsel][kk];
            #pragma unroll
            for (int nj = 0; nj < 4; ++nj)
                bfv[nj] = *(const bf16x8*)&lds[wj + nj * 16 + rsel][kk];
            #pragma unroll
            for (int mi = 0; mi < 4; ++mi)
                #pragma unroll
                for (int nj = 0; nj < 4; ++nj)
                    acc[mi][nj] = __builtin_amdgcn_mfma_f32_16x16x32_bf16(
                        af[mi], bfv[nj], acc[mi][nj], 0, 0, 0);
        }
    }

    // row sums: reduce across the 16 threads sharing each staged row
    float* rsm = rowsum + m * NF;
    #pragma unroll
    for (int j = 0; j < 4; ++j) {
        float v = rs[j];
        v += __shfl_xor(v, 1);
        v += __shfl_xor(v, 2);
        v += __shfl_xor(v, 4);
        v += __shfl_xor(v, 8);
        if ((lane & 15) == 0) atomicAdd(rsm + fr + j * 64, v);
    }

    // gram accumulate (C/D layout: col = lane&15, row = (lane>>4)*4 + reg)
    float* g = gram + (size_t)m * NF * NF;
    const int rowb = (lane >> 4) * 4;
    const int colb = lane & 15;
    #pragma unroll
    for (int mi = 0; mi < 4; ++mi)
        #pragma unroll
        for (int nj = 0; nj < 4; ++nj) {
            const int row = wi + mi * 16 + rowb;
            const int col = wj + nj * 16 + colb;
            #pragma unroll
            for (int r = 0; r < 4; ++r)
                atomicAdd(g + (size_t)(row + r) * NF + col, acc[mi][nj][r]);
        }
}

// ---------------------------------------------------------------------------
// K2: per-matrix: means, cov = (G − S·Sᵀ/L)/(L−1) + eps·I (lower, upper=0),
// then panel-blocked Cholesky in place. One block (256 thr) per matrix.
// ---------------------------------------------------------------------------
__global__ __launch_bounds__(256) void k_chol(const float* __restrict__ gram,
                                              const float* __restrict__ rowsum,
                                              float* __restrict__ Lmat,
                                              float* __restrict__ mean_all) {
    const int m = blockIdx.x;
    const int t = threadIdx.x;
    const float* __restrict__ g = gram + (size_t)m * NF * NF;
    const float* __restrict__ S = rowsum + m * NF;
    float* __restrict__ Lb = Lmat + (size_t)m * NF * NF;

    mean_all[m * NF + t] = S[t] * (1.f / (float)LSP);

    const float Sj      = S[t];
    const float invLn   = 1.f / (float)LSP;
    const float invLm1  = 1.f / (float)(LSP - 1);
    for (int i = 0; i < NF; ++i) {
        float v = 0.f;
        if (i >= t) {
            v = (g[(size_t)i * NF + t] - S[i] * Sj * invLn) * invLm1;
            if (i == t) v += EPS_J;
        }
        Lb[(size_t)i * NF + t] = v;
    }
    __syncthreads();

    __shared__ float panT[32][260];   // panT[c][r] = A[r][jb+c]

    for (int jb = 0; jb < NF; jb += 32) {
        // load panel transposed (thread t = row t reads its 32 panel cols)
        #pragma unroll
        for (int c = 0; c < 32; c += 4) {
            float4 v = *(const float4*)(Lb + (size_t)t * NF + jb + c);
            panT[c + 0][t] = v.x;
            panT[c + 1][t] = v.y;
            panT[c + 2][t] = v.z;
            panT[c + 3][t] = v.w;
        }
        __syncthreads();

        // factor the 32-wide panel
        for (int j = 0; j < 32; ++j) {
            const int jc = jb + j;
            const float d    = panT[j][jc];
            const float sq   = sqrtf(d);
            const float invs = 1.f / sq;
            const float invd = 1.f / d;
            const float myv  = panT[j][t];
            const float sc   = (t == jc) ? sq : myv * invs;
            if (t > jc) {
                const float ms = myv * invd;
                for (int c = j + 1; c < 32; ++c)
                    panT[c][t] -= ms * panT[j][jb + c];
            }
            __syncthreads();
            if (t >= jc) panT[j][t] = sc;
            __syncthreads();
        }

        // write back panel (lower part only; upper stays 0)
        for (int j = 0; j < 32; ++j) {
            const int jc = jb + j;
            if (t >= jc) Lb[(size_t)t * NF + jc] = panT[j][t];
        }
        __syncthreads();

        // trailing syrk update: A[r][c] -= Σ_j L[r][jb+j]·L[c][jb+j], 8x8 tiles
        const int R0 = jb + 32;
        if (R0 < NF) {
            const int nt     = (NF - R0) >> 3;
            const int ntiles = nt * (nt + 1) / 2;
            for (int tt = t; tt < ntiles; tt += 256) {
                int tr = (int)((sqrtf(8.f * (float)tt + 1.f) - 1.f) * 0.5f);
                while ((tr + 1) * (tr + 2) / 2 <= tt) ++tr;
                while (tr * (tr + 1) / 2 > tt) --tr;
                const int tc = tt - tr * (tr + 1) / 2;
                const int r0 = R0 + tr * 8;
                const int c0 = R0 + tc * 8;
                float a[8][8];
                #pragma unroll
                for (int aa = 0; aa < 8; ++aa) {
                    float4 v0 = *(const float4*)(Lb + (size_t)(r0 + aa) * NF + c0);
                    float4 v1 = *(const float4*)(Lb + (size_t)(r0 + aa) * NF + c0 + 4);
                    a[aa][0] = v0.x; a[aa][1] = v0.y; a[aa][2] = v0.z; a[aa][3] = v0.w;
                    a[aa][4] = v1.x; a[aa][5] = v1.y; a[aa][6] = v1.z; a[aa][7] = v1.w;
                }
                for (int j = 0; j < 32; ++j) {
                    float4 u0 = *(const float4*)&panT[j][r0];
                    float4 u1 = *(const float4*)&panT[j][r0 + 4];
                    float4 w0 = *(const float4*)&panT[j][c0];
                    float4 w1 = *(const float4*)&panT[j][c0 + 4];
                    const float lr[8] = {u0.x,u0.y,u0.z,u0.w,u1.x,u1.y,u1.z,u1.w};
                    const float lc[8] = {w0.x,w0.y,w0.z,w0.w,w1.x,w1.y,w1.z,w1.w};
                    #pragma unroll
                    for (int aa = 0; aa < 8; ++aa)
                        #pragma unroll
                        for (int bb = 0; bb < 8; ++bb)
                            a[aa][bb] -= lr[aa] * lc[bb];
                }
                if (tr > tc) {
                    #pragma unroll
                    for (int aa = 0; aa < 8; ++aa) {
                        float4 v0 = {a[aa][0], a[aa][1], a[aa][2], a[aa][3]};
                        float4 v1 = {a[aa][4], a[aa][5], a[aa][6], a[aa][7]};
                        *(float4*)(Lb + (size_t)(r0 + aa) * NF + c0)     = v0;
                        *(float4*)(Lb + (size_t)(r0 + aa) * NF + c0 + 4) = v1;
                    }
                } else {
                    #pragma unroll
                    for (int aa = 0; aa < 8; ++aa)
                        #pragma unroll
                        for (int bb = 0; bb < 8; ++bb)
                            if (c0 + bb <= r0 + aa)
                                Lb[(size_t)(r0 + aa) * NF + c0 + bb] = a[aa][bb];
                }
            }
        }
        __syncthreads();
    }
}

// ---------------------------------------------------------------------------
// K3: inv(Lc) columns by forward substitution. One wave per column.
// grid 512 blocks x 256 thr = 2048 waves = 8 matrices x 256 columns.
// ---------------------------------------------------------------------------
__global__ __launch_bounds__(256) void k_inv(const float* __restrict__ Lmat,
                                             float* __restrict__ invL) {
    const int t    = threadIdx.x;
    const int lane = t & 63;
    const int w    = t >> 6;
    const int task = blockIdx.x * 4 + w;
    const int m    = task >> 8;
    const int c    = task & 255;
    const float* __restrict__ Lb = Lmat + (size_t)m * NF * NF;
    float* __restrict__ V = invL + (size_t)m * NF * NF;

    __shared__ float vbuf[4][NF];
    float* vb = vbuf[w];

    for (int i = lane; i < c; i += 64)
        V[(size_t)i * NF + c] = 0.f;

    for (int i = c; i < NF; ++i) {
        float s = 0.f;
        for (int k = c + lane; k < i; k += 64)
            s += Lb[(size_t)i * NF + k] * vb[k];
        s += __shfl_xor(s, 32);
        s += __shfl_xor(s, 16);
        s += __shfl_xor(s, 8);
        s += __shfl_xor(s, 4);
        s += __shfl_xor(s, 2);
        s += __shfl_xor(s, 1);
        const float v = (((i == c) ? 1.f : 0.f) - s) / Lb[(size_t)i * NF + i];
        if (lane == 0) {
            vb[i] = v;
            V[(size_t)i * NF + c] = v;
        }
    }
}

// ---------------------------------------------------------------------------
// K4: T = Ls·inv(Lc) (fp32 tiled GEMM) -> Tbf (bf16), plus bias partials:
// bias[i] -= Σ T[i][k]·c_mean[k].  grid (4 tiles, 8 batches), 256 thr.
// ---------------------------------------------------------------------------
__global__ __launch_bounds__(256) void k_tmat(const float* __restrict__ Lmat,
                                              const float* __restrict__ invL,
                                              const float* __restrict__ mean_all,
                                              short* __restrict__ Tbf,
                                              float* __restrict__ bias) {
    const int b  = blockIdx.y;
    const int ti = blockIdx.x & 1;
    const int tj = blockIdx.x >> 1;
    const float* __restrict__ A  = Lmat + (size_t)(BATCH + b) * NF * NF;  // Ls
    const float* __restrict__ Bm = invL + (size_t)b * NF * NF;            // inv(Lc)

    __shared__ float As[16][132];
    __shared__ float Bs[16][132];

    const int t  = threadIdx.x;
    const int tx = t & 15;
    const int ty = t >> 4;

    float acc[8][8];
    #pragma unroll
    for (int i = 0; i < 8; ++i)
        #pragma unroll
        for (int j = 0; j < 8; ++j) acc[i][j] = 0.f;

    for (int k0 = 0; k0 < NF; k0 += 16) {
        __syncthreads();
        #pragma unroll
        for (int s2 = 0; s2 < 8; ++s2) {
            const int idx = t + s2 * 256;
            const int i   = idx >> 4;
            const int kk  = idx & 15;
            As[kk][i] = A[(size_t)(ti * 128 + i) * NF + k0 + kk];
        }
        #pragma unroll
        for (int s2 = 0; s2 < 8; ++s2) {
            const int idx = t + s2 * 256;
            const int j   = idx & 127;
            const int kk  = idx >> 7;
            Bs[kk][j] = Bm[(size_t)(k0 + kk) * NF + tj * 128 + j];
        }
        __syncthreads();
        #pragma unroll
        for (int kk = 0; kk < 16; ++kk) {
            float4 a0 = *(const float4*)&As[kk][ty * 8];
            float4 a1 = *(const float4*)&As[kk][ty * 8 + 4];
            float4 b0 = *(const float4*)&Bs[kk][tx * 8];
            float4 b1 = *(const float4*)&Bs[kk][tx * 8 + 4];
            const float ar[8] = {a0.x,a0.y,a0.z,a0.w,a1.x,a1.y,a1.z,a1.w};
            const float br[8] = {b0.x,b0.y,b0.z,b0.w,b1.x,b1.y,b1.z,b1.w};
            #pragma unroll
            for (int aa = 0; aa < 8; ++aa)
                #pragma unroll
                for (int bb = 0; bb < 8; ++bb)
                    acc[aa][bb] += ar[aa] * br[bb];
        }
    }

    const int row0 = ti * 128 + ty * 8;
    const int col0 = tj * 128 + tx * 8;
    const float* cmean = mean_all + b * NF;   // content means
    float cm[8];
    #pragma unroll
    for (int cc = 0; cc < 8; ++cc) cm[cc] = cmean[col0 + cc];

    short* Tb = Tbf + (size_t)b * NF * NF;
    #pragma unroll
    for (int aa = 0; aa < 8; ++aa) {
        float p = 0.f;
        #pragma unroll
        for (int cc = 0; cc < 8; ++cc) {
            Tb[(size_t)(row0 + aa) * NF + col0 + cc] = f2bf(acc[aa][cc]);
            p += acc[aa][cc] * cm[cc];
        }
        atomicAdd(bias + b * NF + row0 + aa, -p);
    }
}

// ---------------------------------------------------------------------------
// K5: out = T·xc + (bias + s_mean). bf16 MFMA, tile 256(i) x 64(l), K=256.
// grid (256 l-tiles, 8 batches), 256 thr (4 waves of 64x64).
// ---------------------------------------------------------------------------
__global__ __launch_bounds__(256) void k_out(const float* __restrict__ cont,
                                             const short* __restrict__ Tbf,
                                             const float* __restrict__ bias,
                                             const float* __restrict__ mean_all,
                                             float* __restrict__ out) {
    const int b  = blockIdx.y;
    const int l0 = blockIdx.x * 64;
    const float* __restrict__ X  = cont + (size_t)b * NF * LSP;
    const short* __restrict__ Tb = Tbf + (size_t)b * NF * NF;
    float* __restrict__ O = out + (size_t)b * NF * LSP;

    __shared__ short a_s[256][72];   // T rows x 64 k (bf16)
    __shared__ short b_s[64][72];    // Xᵀ: [l][k] (bf16)
    __shared__ float bias_s[NF];

    const int t    = threadIdx.x;
    const int lane = t & 63;
    const int w    = t >> 6;

    bias_s[t] = bias[b * NF + t] + mean_all[(BATCH + b) * NF + t];

    f32x4 acc[4][4];
    #pragma unroll
    for (int i = 0; i < 4; ++i)
        #pragma unroll
        for (int j = 0; j < 4; ++j) { f32x4 z = {0.f, 0.f, 0.f, 0.f}; acc[i][j] = z; }

    const int kb = (t >> 4) * 4;   // k base for B staging
    const int lb = (t & 15) * 4;   // l base for B staging
    const int fr = t >> 4;         // A staging row base
    const int fc = (t & 15) * 4;   // A staging col

    float4 xr[4];
    #pragma unroll
    for (int r = 0; r < 4; ++r)
        xr[r] = *(const float4*)(X + (size_t)(kb + r) * LSP + l0 + lb);

    for (int step = 0; step < 4; ++step) {
        const int k0 = step * 64;
        __syncthreads();
        // A stage: T rows (bf16 already)
        #pragma unroll
        for (int s2 = 0; s2 < 16; ++s2) {
            const int row = fr + s2 * 16;
            *(short4v*)&a_s[row][fc] = *(const short4v*)(Tb + (size_t)row * NF + k0 + fc);
        }
        // B stage: 4x4 register transpose -> b_s[l][k]
        {
            short4v c0v = { f2bf(xr[0].x), f2bf(xr[1].x), f2bf(xr[2].x), f2bf(xr[3].x) };
            short4v c1v = { f2bf(xr[0].y), f2bf(xr[1].y), f2bf(xr[2].y), f2bf(xr[3].y) };
            short4v c2v = { f2bf(xr[0].z), f2bf(xr[1].z), f2bf(xr[2].z), f2bf(xr[3].z) };
            short4v c3v = { f2bf(xr[0].w), f2bf(xr[1].w), f2bf(xr[2].w), f2bf(xr[3].w) };
            *(short4v*)&b_s[lb + 0][kb] = c0v;
            *(short4v*)&b_s[lb + 1][kb] = c1v;
            *(short4v*)&b_s[lb + 2][kb] = c2v;
            *(short4v*)&b_s[lb + 3][kb] = c3v;
        }
        __syncthreads();
        if (step < 3) {
            const int k0n = k0 + 64;
            #pragma unroll
            for (int r = 0; r < 4; ++r)
                xr[r] = *(const float4*)(X + (size_t)(k0n + kb + r) * LSP + l0 + lb);
        }
        #pragma unroll
        for (int ks = 0; ks < 2; ++ks) {
            const int kk   = ks * 32 + (lane >> 4) * 8;
            const int rsel = lane & 15;
            bf16x8 af[4], bfv[4];
            #pragma unroll
            for (int mi = 0; mi < 4; ++mi)
                af[mi] = *(const bf16x8*)&a_s[w * 64 + mi * 16 + rsel][kk];
            #pragma unroll
            for (int nj = 0; nj < 4; ++nj)
                bfv[nj] = *(const bf16x8*)&b_s[nj * 16 + rsel][kk];
            #pragma unroll
            for (int mi = 0; mi < 4; ++mi)
                #pragma unroll
                for (int nj = 0; nj < 4; ++nj)
                    acc[mi][nj] = __builtin_amdgcn_mfma_f32_16x16x32_bf16(
                        af[mi], bfv[nj], acc[mi][nj], 0, 0, 0);
        }
    }

    #pragma unroll
    for (int mi = 0; mi < 4; ++mi) {
        const int row = w * 64 + mi * 16 + (lane >> 4) * 4;
        #pragma unroll
        for (int nj = 0; nj < 4; ++nj) {
            const int col = l0 + nj * 16 + (lane & 15);
            #pragma unroll
            for (int r = 0; r < 4; ++r)
                O[(size_t)(row + r) * LSP + col] = acc[mi][nj][r] + bias_s[row + r];
        }
    }
}

// ---------------------------------------------------------------------------
extern "C" void kernel_launch(void* const* d_in, const int* in_sizes, int n_in,
                              void* d_out, int out_size, void* d_ws, size_t ws_size,
                              hipStream_t stream) {
    (void)in_sizes; (void)n_in; (void)out_size; (void)ws_size;
    const float* cont = (const float*)d_in[0];
    const float* styl = (const float*)d_in[1];
    float* out = (float*)d_out;

    float* ws       = (float*)d_ws;
    float* gram     = ws;                        // 16*65536 f32 (4 MB)
    float* bias     = gram + 16 * 65536;         // 8*256
    float* rowsum   = bias + 2048;               // 16*256
    float* mean_all = rowsum + 4096;             // 16*256
    float* Lmat     = mean_all + 4096;           // 16*65536 f32 (4 MB)
    float* invL     = Lmat + 16 * 65536;         // 8*65536 f32 (2 MB)
    short* Tbf      = (short*)(invL + 8 * 65536);// 8*65536 bf16 (1 MB)

    const size_t zero_bytes = (size_t)(16 * 65536 + 2048 + 4096) * sizeof(float);
    hipMemsetAsync(gram, 0, zero_bytes, stream);

    k_cov <<<dim3(16, 16), 1024, 0, stream>>>(cont, styl, gram, rowsum);
    k_chol<<<16,          256,  0, stream>>>(gram, rowsum, Lmat, mean_all);
    k_inv <<<512,         256,  0, stream>>>(Lmat, invL);
    k_tmat<<<dim3(4, 8),  256,  0, stream>>>(Lmat, invL, mean_all, Tbf, bias);
    k_out <<<dim3(256, 8),256,  0, stream>>>(cont, Tbf, bias, mean_all, out);
}

// Round 2
// 806.142 us; speedup vs baseline: 1.3207x; 1.3207x over previous
//
#include <hip/hip_runtime.h>

// cWCT: out = Ls·inv(Lc)·(xc − c_mean) + s_mean  =  T·xc + bias
// B=8, N=256, L=16384. fp32 in/out; bf16 MFMA for the big GEMMs.
// Round 2: k_chol rewritten (3 barriers/panel: wave-reg diag factor,
// thread-parallel trsm, MFMA syrk). k_inv+k_tmat fused into k_solveT
// (T·Lc = Ls row-solve, 2-wide steps, direct bias store).

#define BATCH 8
#define NF    256
#define LSP   16384
#define EPS_J 2e-5f

typedef float f32x4  __attribute__((ext_vector_type(4)));
typedef short bf16x8 __attribute__((ext_vector_type(8)));
typedef short short4v __attribute__((ext_vector_type(4)));

__device__ __forceinline__ short f2bf(float f) {
    unsigned u = __float_as_uint(f);
    u = (u + 0x7FFFu + ((u >> 16) & 1u)) >> 16;   // RNE to bf16
    return (short)u;
}

// ---------------------------------------------------------------------------
// K1: batched syrk  gram[m] += A·Aᵀ (bf16 MFMA, split-K) + fp32 row sums.
// grid (splitk=16, m=16), 1024 threads. (unchanged from round 1 — proven)
// ---------------------------------------------------------------------------
__global__ __launch_bounds__(1024) void k_cov(const float* __restrict__ cont,
                                              const float* __restrict__ styl,
                                              float* __restrict__ gram,
                                              float* __restrict__ rowsum) {
    const int kc = blockIdx.x;
    const int m  = blockIdx.y;
    const float* __restrict__ src = (m < BATCH)
        ? cont + (size_t)m * NF * LSP
        : styl + (size_t)(m - BATCH) * NF * LSP;

    __shared__ short lds[256][72];

    const int t    = threadIdx.x;
    const int lane = t & 63;
    const int w    = t >> 6;
    const int wi   = (w & 3) * 64;
    const int wj   = (w >> 2) * 64;
    const int fr   = t >> 4;
    const int fc   = (t & 15) * 4;

    f32x4 acc[4][4];
    #pragma unroll
    for (int i = 0; i < 4; ++i)
        #pragma unroll
        for (int j = 0; j < 4; ++j) { f32x4 z = {0.f,0.f,0.f,0.f}; acc[i][j] = z; }

    float rs[4] = {0.f, 0.f, 0.f, 0.f};

    const size_t kbase = (size_t)kc * 1024;
    float4 pre[4];
    #pragma unroll
    for (int j = 0; j < 4; ++j)
        pre[j] = *(const float4*)(src + (size_t)(fr + j * 64) * LSP + kbase + fc);

    for (int step = 0; step < 16; ++step) {
        __syncthreads();
        #pragma unroll
        for (int j = 0; j < 4; ++j) {
            float4 v = pre[j];
            rs[j] += v.x + v.y + v.z + v.w;
            short4v b4 = { f2bf(v.x), f2bf(v.y), f2bf(v.z), f2bf(v.w) };
            *(short4v*)&lds[fr + j * 64][fc] = b4;
        }
        __syncthreads();
        if (step < 15) {
            const size_t k0n = kbase + (size_t)(step + 1) * 64;
            #pragma unroll
            for (int j = 0; j < 4; ++j)
                pre[j] = *(const float4*)(src + (size_t)(fr + j * 64) * LSP + k0n + fc);
        }
        #pragma unroll
        for (int ks = 0; ks < 2; ++ks) {
            const int kk   = ks * 32 + (lane >> 4) * 8;
            const int rsel = lane & 15;
            bf16x8 af[4], bfv[4];
            #pragma unroll
            for (int mi = 0; mi < 4; ++mi)
                af[mi] = *(const bf16x8*)&lds[wi + mi * 16 + rsel][kk];
            #pragma unroll
            for (int nj = 0; nj < 4; ++nj)
                bfv[nj] = *(const bf16x8*)&lds[wj + nj * 16 + rsel][kk];
            #pragma unroll
            for (int mi = 0; mi < 4; ++mi)
                #pragma unroll
                for (int nj = 0; nj < 4; ++nj)
                    acc[mi][nj] = __builtin_amdgcn_mfma_f32_16x16x32_bf16(
                        af[mi], bfv[nj], acc[mi][nj], 0, 0, 0);
        }
    }

    float* rsm = rowsum + m * NF;
    #pragma unroll
    for (int j = 0; j < 4; ++j) {
        float v = rs[j];
        v += __shfl_xor(v, 1);
        v += __shfl_xor(v, 2);
        v += __shfl_xor(v, 4);
        v += __shfl_xor(v, 8);
        if ((lane & 15) == 0) atomicAdd(rsm + fr + j * 64, v);
    }

    float* g = gram + (size_t)m * NF * NF;
    const int rowb = (lane >> 4) * 4;
    const int colb = lane & 15;
    #pragma unroll
    for (int mi = 0; mi < 4; ++mi)
        #pragma unroll
        for (int nj = 0; nj < 4; ++nj) {
            const int row = wi + mi * 16 + rowb;
            const int col = wj + nj * 16 + colb;
            #pragma unroll
            for (int r = 0; r < 4; ++r)
                atomicAdd(g + (size_t)(row + r) * NF + col, acc[mi][nj][r]);
        }
}

// ---------------------------------------------------------------------------
// K2: cov formation (in-place on gram) + panel Cholesky.
// One block (1024 thr, 16 waves) per matrix. 3 barriers per panel.
// Content matrices (m<8): also write Lc TRANSPOSED into LcT.
// Style matrices: Lg (row-major lower) is the final Ls.
// ---------------------------------------------------------------------------
__global__ __launch_bounds__(1024) void k_chol(float* __restrict__ Lg_all,
                                               const float* __restrict__ rowsum,
                                               float* __restrict__ LcT_all,
                                               float* __restrict__ mean_all) {
    const int m = blockIdx.x;
    float* __restrict__ Lg  = Lg_all + (size_t)m * NF * NF;   // aliases gram[m]
    float* __restrict__ LcT = (m < BATCH) ? (LcT_all + (size_t)m * NF * NF) : nullptr;

    __shared__ float Sm[NF];
    __shared__ float Db[32][33];    // factored diag block (broadcast for trsm)
    __shared__ float rDd[32];       // 1/diag
    __shared__ float Pan[224][33];  // current panel rows below diag (fp32)
    __shared__ short Pb[224][40];   // same, bf16, padded to 80B rows (16B-aligned)

    const int t    = threadIdx.x;
    const int lane = t & 63;
    const int wv   = t >> 6;

    if (t < NF) {
        float s = rowsum[m * NF + t];
        Sm[t] = s;
        mean_all[m * NF + t] = s * (1.f / (float)LSP);
    }
    __syncthreads();

    // cov = (G - S·Sᵀ/L)/(L-1) + eps·I, lower only (upper zeroed), in place
    const float invLn  = 1.f / (float)LSP;
    const float invLm1 = 1.f / (float)(LSP - 1);
    for (int idx = t; idx < NF * NF; idx += 1024) {
        const int r = idx >> 8, c = idx & 255;
        float v = 0.f;
        if (c <= r) {
            v = (Lg[idx] - Sm[r] * Sm[c] * invLn) * invLm1;
            if (c == r) v += EPS_J;
        }
        Lg[idx] = v;
    }
    __syncthreads();

    for (int jb = 0; jb < NF; jb += 32) {
        const int R0 = jb + 32;
        const int R  = NF - R0;      // rows below the diag block (224..0)

        // stage panel rows below diag into Pan (coalesced)
        for (int idx = t; idx < R * 32; idx += 1024) {
            const int rr = idx >> 5, cc = idx & 31;
            Pan[rr][cc] = Lg[(size_t)(R0 + rr) * NF + jb + cc];
        }

        // wave 0, lanes 0..31: factor the 32x32 diag block in registers
        if (t < 32) {
            const int r = t;
            float a[32];
            #pragma unroll
            for (int c = 0; c < 32; ++c)
                a[c] = Lg[(size_t)(jb + r) * NF + jb + c];
            #pragma unroll
            for (int j = 0; j < 32; ++j) {
                const float d   = __shfl(a[j], j);
                const float sq  = sqrtf(d);
                const float inv = 1.f / sq;
                const float lj  = a[j] * inv;   // L[r][j] for r>=j (r==j -> sq)
                a[j] = lj;
                #pragma unroll
                for (int c = j + 1; c < 32; ++c)
                    a[c] -= lj * __shfl(lj, c);     // -= L[r][j]*L[c][j]
                if (r == 0) rDd[j] = inv;
            }
            #pragma unroll
            for (int c = 0; c < 32; ++c) {
                if (c <= r) {
                    const float v = a[c];
                    Lg[(size_t)(jb + r) * NF + jb + c] = v;
                    Db[r][c] = v;
                    if (LcT) LcT[(size_t)(jb + c) * NF + jb + r] = v;
                }
            }
        }
        __syncthreads();   // Db, rDd, Pan ready

        // trsm: one thread per row below diag, 32-step register solve
        if (t < R) {
            float x[32];
            #pragma unroll
            for (int c = 0; c < 32; ++c) x[c] = Pan[t][c];
            #pragma unroll
            for (int c = 0; c < 32; ++c) {
                float acc = x[c];
                #pragma unroll
                for (int k = 0; k < c; ++k) acc -= x[k] * Db[c][k];
                x[c] = acc * rDd[c];
            }
            #pragma unroll
            for (int c = 0; c < 32; ++c) {
                Pan[t][c] = x[c];
                Pb[t][c]  = f2bf(x[c]);
            }
        }
        __syncthreads();   // Pan (solved) + Pb ready

        // write solved panel back (coalesced) + transposed copy for content
        for (int idx = t; idx < R * 32; idx += 1024) {
            const int rr = idx >> 5, cc = idx & 31;
            Lg[(size_t)(R0 + rr) * NF + jb + cc] = Pan[rr][cc];
        }
        if (LcT) {
            #pragma unroll 4
            for (int c = 0; c < 32; ++c)
                for (int rr = t; rr < R; rr += 1024)
                    LcT[(size_t)(jb + c) * NF + R0 + rr] = Pan[rr][c];
        }

        // trailing syrk via MFMA: C[r][c] -= Σ_j P[r][j]·P[c][j], 16x16 tiles
        if (R > 0) {
            const int nt  = R >> 4;
            const int ntt = nt * (nt + 1) / 2;
            for (int tt = wv; tt < ntt; tt += 16) {
                int tr = (int)((sqrtf(8.f * (float)tt + 1.f) - 1.f) * 0.5f);
                while ((tr + 1) * (tr + 2) / 2 <= tt) ++tr;
                while (tr * (tr + 1) / 2 > tt) --tr;
                const int tc = tt - tr * (tr + 1) / 2;
                const int r0 = tr * 16, c0 = tc * 16;   // relative to R0
                bf16x8 af  = *(const bf16x8*)&Pb[r0 + (lane & 15)][(lane >> 4) * 8];
                bf16x8 bfv = *(const bf16x8*)&Pb[c0 + (lane & 15)][(lane >> 4) * 8];
                f32x4 accv = {0.f, 0.f, 0.f, 0.f};
                accv = __builtin_amdgcn_mfma_f32_16x16x32_bf16(af, bfv, accv, 0, 0, 0);
                const int col  = R0 + c0 + (lane & 15);
                const int rowb = R0 + r0 + (lane >> 4) * 4;
                #pragma unroll
                for (int rg = 0; rg < 4; ++rg) {
                    const int row = rowb + rg;
                    if (col <= row)
                        Lg[(size_t)row * NF + col] -= accv[rg];
                }
            }
        }
        __syncthreads();   // trailing updated before next panel
    }
}

// ---------------------------------------------------------------------------
// K3: solve T·Lc = Ls per row of T (T lower-triangular), write Tbf (bf16)
// and bias[i] = s_mean[i] − Σ_k T[i,k]·c_mean[k]. One wave per (b, i).
// grid 512 x 256 thr (4 waves). Lc read via LcT (contiguous columns).
// ---------------------------------------------------------------------------
__global__ __launch_bounds__(256) void k_solveT(const float* __restrict__ Lg_all,
                                                const float* __restrict__ LcT_all,
                                                const float* __restrict__ mean_all,
                                                short* __restrict__ Tbf,
                                                float* __restrict__ bias) {
    const int lane = threadIdx.x & 63;
    const int wv   = threadIdx.x >> 6;
    const int task = blockIdx.x * 4 + wv;
    const int b    = task >> 8;
    const int i    = task & 255;
    const float* __restrict__ Ls  = Lg_all + (size_t)(BATCH + b) * NF * NF + (size_t)i * NF;
    const float* __restrict__ LcT = LcT_all + (size_t)b * NF * NF;

    __shared__ float vbuf[4][NF];
    float* vb = vbuf[wv];
    for (int k = lane; k < NF; k += 64) vb[k] = 0.f;

    int j = i;
    for (; j >= 1; j -= 2) {
        const float* __restrict__ r0 = LcT + (size_t)j * NF;        // Lc[k][j]
        const float* __restrict__ r1 = r0 - NF;                     // Lc[k][j-1]
        float s0 = 0.f, s1 = 0.f;
        for (int k = j + 1 + lane; k <= i; k += 64) {
            const float tk = vb[k];
            s0 += tk * r0[k];
            s1 += tk * r1[k];
        }
        #pragma unroll
        for (int mm = 32; mm >= 1; mm >>= 1) {
            s0 += __shfl_xor(s0, mm);
            s1 += __shfl_xor(s1, mm);
        }
        if (lane == 0) {
            const float tj  = (Ls[j] - s0) / r0[j];
            const float tjm = (Ls[j - 1] - s1 - tj * r1[j]) / r1[j - 1];
            vb[j]     = tj;
            vb[j - 1] = tjm;
        }
    }
    if (j == 0) {
        const float* __restrict__ r0 = LcT;
        float s0 = 0.f;
        for (int k = 1 + lane; k <= i; k += 64) s0 += vb[k] * r0[k];
        #pragma unroll
        for (int mm = 32; mm >= 1; mm >>= 1) s0 += __shfl_xor(s0, mm);
        if (lane == 0) vb[0] = (Ls[0] - s0) / r0[0];
    }

    // bias[i] = s_mean[i] − Σ T[i,k]·c_mean[k]
    const float* __restrict__ cm  = mean_all + b * NF;
    const float* __restrict__ smn = mean_all + (BATCH + b) * NF;
    float dot = 0.f;
    for (int k = lane; k < NF; k += 64) dot += vb[k] * cm[k];
    #pragma unroll
    for (int mm = 32; mm >= 1; mm >>= 1) dot += __shfl_xor(dot, mm);
    if (lane == 0) bias[b * NF + i] = smn[i] - dot;

    short* __restrict__ Tr = Tbf + (size_t)b * NF * NF + (size_t)i * NF;
    const int k4 = lane * 4;
    short4v o = { f2bf(vb[k4]), f2bf(vb[k4 + 1]), f2bf(vb[k4 + 2]), f2bf(vb[k4 + 3]) };
    *(short4v*)&Tr[k4] = o;
}

// ---------------------------------------------------------------------------
// K4: out = T·xc + bias. bf16 MFMA, tile 256(i) x 64(l), K=256.
// grid (256 l-tiles, 8 batches), 256 thr (4 waves of 64x64).
// ---------------------------------------------------------------------------
__global__ __launch_bounds__(256) void k_out(const float* __restrict__ cont,
                                             const short* __restrict__ Tbf,
                                             const float* __restrict__ bias,
                                             float* __restrict__ out) {
    const int b  = blockIdx.y;
    const int l0 = blockIdx.x * 64;
    const float* __restrict__ X  = cont + (size_t)b * NF * LSP;
    const short* __restrict__ Tb = Tbf + (size_t)b * NF * NF;
    float* __restrict__ O = out + (size_t)b * NF * LSP;

    __shared__ short a_s[256][72];
    __shared__ short b_s[64][72];
    __shared__ float bias_s[NF];

    const int t    = threadIdx.x;
    const int lane = t & 63;
    const int w    = t >> 6;

    bias_s[t] = bias[b * NF + t];

    f32x4 acc[4][4];
    #pragma unroll
    for (int i = 0; i < 4; ++i)
        #pragma unroll
        for (int j = 0; j < 4; ++j) { f32x4 z = {0.f,0.f,0.f,0.f}; acc[i][j] = z; }

    const int kb = (t >> 4) * 4;
    const int lb = (t & 15) * 4;
    const int fr = t >> 4;
    const int fc = (t & 15) * 4;

    float4 xr[4];
    #pragma unroll
    for (int r = 0; r < 4; ++r)
        xr[r] = *(const float4*)(X + (size_t)(kb + r) * LSP + l0 + lb);

    for (int step = 0; step < 4; ++step) {
        const int k0 = step * 64;
        __syncthreads();
        #pragma unroll
        for (int s2 = 0; s2 < 16; ++s2) {
            const int row = fr + s2 * 16;
            *(short4v*)&a_s[row][fc] = *(const short4v*)(Tb + (size_t)row * NF + k0 + fc);
        }
        {
            short4v c0v = { f2bf(xr[0].x), f2bf(xr[1].x), f2bf(xr[2].x), f2bf(xr[3].x) };
            short4v c1v = { f2bf(xr[0].y), f2bf(xr[1].y), f2bf(xr[2].y), f2bf(xr[3].y) };
            short4v c2v = { f2bf(xr[0].z), f2bf(xr[1].z), f2bf(xr[2].z), f2bf(xr[3].z) };
            short4v c3v = { f2bf(xr[0].w), f2bf(xr[1].w), f2bf(xr[2].w), f2bf(xr[3].w) };
            *(short4v*)&b_s[lb + 0][kb] = c0v;
            *(short4v*)&b_s[lb + 1][kb] = c1v;
            *(short4v*)&b_s[lb + 2][kb] = c2v;
            *(short4v*)&b_s[lb + 3][kb] = c3v;
        }
        __syncthreads();
        if (step < 3) {
            const int k0n = k0 + 64;
            #pragma unroll
            for (int r = 0; r < 4; ++r)
                xr[r] = *(const float4*)(X + (size_t)(k0n + kb + r) * LSP + l0 + lb);
        }
        #pragma unroll
        for (int ks = 0; ks < 2; ++ks) {
            const int kk   = ks * 32 + (lane >> 4) * 8;
            const int rsel = lane & 15;
            bf16x8 af[4], bfv[4];
            #pragma unroll
            for (int mi = 0; mi < 4; ++mi)
                af[mi] = *(const bf16x8*)&a_s[w * 64 + mi * 16 + rsel][kk];
            #pragma unroll
            for (int nj = 0; nj < 4; ++nj)
                bfv[nj] = *(const bf16x8*)&b_s[nj * 16 + rsel][kk];
            #pragma unroll
            for (int mi = 0; mi < 4; ++mi)
                #pragma unroll
                for (int nj = 0; nj < 4; ++nj)
                    acc[mi][nj] = __builtin_amdgcn_mfma_f32_16x16x32_bf16(
                        af[mi], bfv[nj], acc[mi][nj], 0, 0, 0);
        }
    }

    #pragma unroll
    for (int mi = 0; mi < 4; ++mi) {
        const int row = w * 64 + mi * 16 + (lane >> 4) * 4;
        #pragma unroll
        for (int nj = 0; nj < 4; ++nj) {
            const int col = l0 + nj * 16 + (lane & 15);
            #pragma unroll
            for (int r = 0; r < 4; ++r)
                O[(size_t)(row + r) * LSP + col] = acc[mi][nj][r] + bias_s[row + r];
        }
    }
}

// ---------------------------------------------------------------------------
extern "C" void kernel_launch(void* const* d_in, const int* in_sizes, int n_in,
                              void* d_out, int out_size, void* d_ws, size_t ws_size,
                              hipStream_t stream) {
    (void)in_sizes; (void)n_in; (void)out_size; (void)ws_size;
    const float* cont = (const float*)d_in[0];
    const float* styl = (const float*)d_in[1];
    float* out = (float*)d_out;

    float* ws       = (float*)d_ws;
    float* gram     = ws;                         // 16*65536 f32 — reused as Lg
    float* rowsum   = gram + 16 * 65536;          // 16*256
    float* mean_all = rowsum + 4096;              // 16*256
    float* bias     = mean_all + 4096;            // 8*256
    float* LcT      = bias + 2048;                // 8*65536 f32 (2 MB)
    short* Tbf      = (short*)(LcT + 8 * 65536);  // 8*65536 bf16 (1 MB)

    // zero gram + rowsum (atomic accumulation targets)
    hipMemsetAsync(gram, 0, (size_t)(16 * 65536 + 4096) * sizeof(float), stream);

    k_cov   <<<dim3(16, 16), 1024, 0, stream>>>(cont, styl, gram, rowsum);
    k_chol  <<<16,           1024, 0, stream>>>(gram, rowsum, LcT, mean_all);
    k_solveT<<<512,          256,  0, stream>>>(gram, LcT, mean_all, Tbf, bias);
    k_out   <<<dim3(256, 8), 256,  0, stream>>>(cont, Tbf, bias, out);
}